// Round 3
// baseline (565.084 us; speedup 1.0000x reference)
//
#include <hip/hip_runtime.h>

#define FF 512
#define LL 12288
#define NJC 1556   // XB chunk count: max jc touched = 1554 (incl. K-roundup + 2-deep prefetch)
#define NR 128     // XB rows = 16 shifts x 8 batches

typedef _Float16 half8 __attribute__((ext_vector_type(8)));
typedef float    f32x16 __attribute__((ext_vector_type(16)));

// ---------------- Prologue 1: kernel fp32 -> f16, 32x32x16 MFMA-A-fragment tiled
// Chunk (fgt, kc, lane): elem_i = kernel[fgt*32 + (lane&31)][kc*16 + (lane>>5)*8 + i]
__global__ __launch_bounds__(256) void build_At(const float* __restrict__ kern,
                                                _Float16* __restrict__ At) {
    int tid  = blockIdx.x * 256 + threadIdx.x;      // 786432 = 512*12288/8
    int lane = tid & 63;
    int rest = tid >> 6;                            // fgt*768 + kc
    int kc   = rest % 768;
    int fgt  = rest / 768;
    int f    = fgt * 32 + (lane & 31);
    int d0   = kc * 16 + (lane >> 5) * 8;
    const float* src = kern + (size_t)f * LL + d0;
    half8 v;
#pragma unroll
    for (int i = 0; i < 8; ++i) v[i] = (_Float16)src[i];
    ((half8*)At)[tid] = v;
}

// ---------------- Prologue 2: B chunk-major layout (UNCHANGED) ----------------
// XB[jc][r] (16B chunks): r = s*8 + b, s in [0,16). elem_i = x_b[LL-1-(8jc+i)-s]
// (zero when index < 0 -> causal mask, incl. the whole jc >= 1536 pad tail).
__global__ __launch_bounds__(256) void build_XB(const int* __restrict__ ex,
                                                _Float16* __restrict__ XB) {
    int tid = blockIdx.x * 256 + threadIdx.x;       // 199168 = NJC*NR
    if (tid >= NJC * NR) return;
    int r  = tid & 127;
    int jc = tid >> 7;
    int s  = r >> 3, b = r & 7;
    int j0 = jc * 8;
    half8 v;
#pragma unroll
    for (int i = 0; i < 8; ++i) {
        int idx = LL - 1 - (j0 + i) - s;
        float x = 0.f;
        if (idx >= 0) x = (float)ex[b * LL + idx] * 0.5f - 1.0f;
        v[i] = (_Float16)x;
    }
    ((half8*)XB)[tid] = v;
}

// ---------------- Prologue 3: out = dense_b broadcast ----------------------
__global__ __launch_bounds__(256) void init_out(const float* __restrict__ db,
                                                float* __restrict__ out) {
    int tid = blockIdx.x * 256 + threadIdx.x;       // 393216
    out[tid] = db[tid & 3];
}

__device__ __forceinline__ void gl_lds16(const half8* g, half8* l) {
    __builtin_amdgcn_global_load_lds((const __attribute__((address_space(1))) void*)g,
                                     (__attribute__((address_space(3))) void*)l, 16, 0, 0);
}

// ---------------- Main: A via LDS (BK=128 macro-steps), B register-direct --
// Block 128f x 256cols (8b x 32n), 4 waves each owning 128f x 64col:
// 4x2 mfma_32x32x16_f16 per kc16, batched 2 kc per window (8 ds_read -> 16 MFMA)
// to widen the MFMA burst between LDS waits. Counted-vmcnt barrier (T4): the 8
// A-staging gl_lds issue first, B loads after; s_waitcnt vmcnt(16)+s_barrier
// leaves all B prefetch in flight across the barrier. setprio(1) on MFMA (T5).
__global__ __launch_bounds__(256, 2) void conv_main(const _Float16* __restrict__ At,
                                                    const _Float16* __restrict__ XB,
                                                    const float* __restrict__ bias,
                                                    const float* __restrict__ dw,
                                                    float* __restrict__ out) {
    __shared__ half8 Abuf[2][8][4][64];   // 64 KB: [buf][kc][ftile][lane]

    int bx    = blockIdx.x;
    int slot  = bx & 7;                // XCD pin: f_blk per XCD pair for L2 reuse
    int f_blk = slot >> 1;             // [0,4)
    int n_blk = 383 - ((bx >> 3) * 2 + (slot & 1));   // largest K first
    int n0 = n_blk << 5;
    int M  = (n_blk + 4) >> 2;         // ceil((n_blk+1)/4) macro (BK=128) steps

    int tid  = threadIdx.x;
    int lane = tid & 63;
    int wid  = tid >> 6;
    int bb   = lane & 7;               // batch
    int nq   = (lane >> 3) & 3;        // position within 4-col group
    int kh   = lane >> 5;              // K-half within kc16

    // A staging: wave wid stages kc_local {2wid, 2wid+1} x ft {0..3}; 1KB/load.
    const half8* Ag = (const half8*)At;
    const half8* ag[8];
#pragma unroll
    for (int u = 0; u < 8; ++u) {
        int kcl = wid * 2 + (u >> 2);
        int ft  = u & 3;
        ag[u] = Ag + ((size_t)(f_blk * 4 + ft) * 768 + kcl) * 64 + lane;
    }

    // B pointers (half8 units): element_i at [jc*128 + s*8 + bb] = x_bb[LL-1-8jc-s-i].
    // Need x_bb[n - (16*kc + 8*kh + i)]  ->  8*jc + s = LL-1 - n + 8*kh + 16*kc.
    const half8* Bg = (const half8*)XB;
    const half8* pB[2];
#pragma unroll
    for (int cf = 0; cf < 2; ++cf) {
        int n  = n0 + wid * 8 + cf * 4 + nq;
        int T  = LL - 1 - n + 8 * kh;
        pB[cf] = Bg + (size_t)(T >> 3) * 128 + (T & 7) * 8 + bb;
    }

    f32x16 acc[4][2];
#pragma unroll
    for (int rf = 0; rf < 4; ++rf)
#pragma unroll
        for (int cf = 0; cf < 2; ++cf)
#pragma unroll
            for (int i = 0; i < 16; ++i) acc[rf][cf][i] = 0.f;

    // prologue: stage macro 0 -> buf0 (8 gl_lds first), then B(kc0), B(kc1)
#pragma unroll
    for (int u = 0; u < 8; ++u)
        gl_lds16(ag[u], &Abuf[0][wid * 2 + (u >> 2)][u & 3][lane]);
    __builtin_amdgcn_sched_barrier(0);
    half8 bc[2][2], bn[2][2];
#pragma unroll
    for (int cf = 0; cf < 2; ++cf) {
        bc[0][cf] = pB[cf][0];
        bc[1][cf] = pB[cf][256];
        pB[cf] += 512;                 // now points at kc-step 2
    }
    __builtin_amdgcn_sched_barrier(0);
    asm volatile("s_waitcnt vmcnt(4)" ::: "memory");   // 8 gl_lds done; B in flight
    __builtin_amdgcn_s_barrier();
    __builtin_amdgcn_sched_barrier(0);

    for (int mc = 0; mc < M; ++mc) {
        int buf = mc & 1;
        // stage next macro (always; final-macro overrun stays inside d_ws, never read)
        size_t oa = (size_t)(mc + 1) * 512;           // 8 kc x 64 chunks
#pragma unroll
        for (int u = 0; u < 8; ++u)
            gl_lds16(ag[u] + oa, &Abuf[buf ^ 1][wid * 2 + (u >> 2)][u & 3][lane]);
        __builtin_amdgcn_sched_barrier(0);            // pin: gl_lds before all B loads

#pragma unroll
        for (int w = 0; w < 4; ++w) {                 // 2 kc per window
#pragma unroll
            for (int cf = 0; cf < 2; ++cf) {          // prefetch kc+2, kc+3
                bn[0][cf] = pB[cf][0];
                bn[1][cf] = pB[cf][256];
                pB[cf] += 512;
            }
            half8 a2[2][4];
#pragma unroll
            for (int h = 0; h < 2; ++h)
#pragma unroll
                for (int rf = 0; rf < 4; ++rf)
                    a2[h][rf] = Abuf[buf][2 * w + h][rf][lane];
            __builtin_amdgcn_s_setprio(1);
#pragma unroll
            for (int h = 0; h < 2; ++h)
#pragma unroll
                for (int rf = 0; rf < 4; ++rf)
#pragma unroll
                    for (int cf = 0; cf < 2; ++cf)
                        acc[rf][cf] = __builtin_amdgcn_mfma_f32_32x32x16_f16(
                            a2[h][rf], bc[h][cf], acc[rf][cf], 0, 0, 0);
            __builtin_amdgcn_s_setprio(0);
#pragma unroll
            for (int h = 0; h < 2; ++h)
#pragma unroll
                for (int cf = 0; cf < 2; ++cf) bc[h][cf] = bn[h][cf];
        }

        __builtin_amdgcn_sched_barrier(0);
        // All 8 gl_lds (oldest vmem) done; up to 16 B loads stay in flight.
        asm volatile("s_waitcnt vmcnt(16)" ::: "memory");
        __builtin_amdgcn_s_barrier();
        __builtin_amdgcn_sched_barrier(0);
    }

    // Epilogue: bias + relu + dense over all 128 f rows of the block.
    // C/D layout (32x32): col = lane&31 = nq*8+bb, row = (reg&3)+8*(reg>>2)+4*kh.
    float p[2][4];
#pragma unroll
    for (int cf = 0; cf < 2; ++cf)
#pragma unroll
        for (int c = 0; c < 4; ++c) p[cf][c] = 0.f;

#pragma unroll
    for (int rf = 0; rf < 4; ++rf) {
#pragma unroll
        for (int reg = 0; reg < 16; ++reg) {
            int f = f_blk * 128 + rf * 32 + (reg & 3) + 8 * (reg >> 2) + 4 * kh;
            float bs = bias[f];
            float4 w = *(const float4*)(dw + (size_t)f * 4);
#pragma unroll
            for (int cf = 0; cf < 2; ++cf) {
                float y = fmaxf(acc[rf][cf][reg] + bs, 0.f);
                p[cf][0] += y * w.x; p[cf][1] += y * w.y;
                p[cf][2] += y * w.z; p[cf][3] += y * w.w;
            }
        }
    }
    // combine the two K-half lane groups (same col, disjoint f rows)
#pragma unroll
    for (int cf = 0; cf < 2; ++cf)
#pragma unroll
        for (int c = 0; c < 4; ++c)
            p[cf][c] += __shfl_xor(p[cf][c], 32, 64);
    if (kh == 0) {
#pragma unroll
        for (int cf = 0; cf < 2; ++cf) {
            int n = n0 + wid * 8 + cf * 4 + nq;
            float* o = out + ((size_t)bb * LL + n) * 4;
#pragma unroll
            for (int c = 0; c < 4; ++c) atomicAdd(o + c, p[cf][c]);
        }
    }
}

extern "C" void kernel_launch(void* const* d_in, const int* in_sizes, int n_in,
                              void* d_out, int out_size, void* d_ws, size_t ws_size,
                              hipStream_t stream) {
    const int*   ex   = (const int*)d_in[0];
    const float* kern = (const float*)d_in[1];
    const float* bias = (const float*)d_in[2];
    const float* dw   = (const float*)d_in[3];
    const float* db   = (const float*)d_in[4];
    float* out = (float*)d_out;

    _Float16* At = (_Float16*)d_ws;                                   // 12.58 MB
    _Float16* XB = (_Float16*)((char*)d_ws + (size_t)FF * LL * 2);    // +3.05 MB

    hipLaunchKernelGGL(build_At, dim3(3072), dim3(256), 0, stream, kern, At);
    hipLaunchKernelGGL(build_XB, dim3(778),  dim3(256), 0, stream, ex, XB);
    hipLaunchKernelGGL(init_out, dim3(1536), dim3(256), 0, stream, db, out);
    hipLaunchKernelGGL(conv_main, dim3(1536), dim3(256), 0, stream, At, XB, bias, dw, out);
}

// Round 4
// 526.566 us; speedup vs baseline: 1.0731x; 1.0731x over previous
//
#include <hip/hip_runtime.h>

#define FF 512
#define LL 12288
#define NJC 1556   // XB chunk count: max jc touched <= 1553 (incl. K-roundup + prefetch)
#define NR 128     // XB rows = 16 shifts x 8 batches

typedef _Float16 half8 __attribute__((ext_vector_type(8)));
typedef float    f32x4 __attribute__((ext_vector_type(4)));

// ---------------- Prologue 1: kernel fp32 -> f16, MFMA-A-fragment tiled ----
// At chunk (ft,dc,lane): elem_i = kernel[ft*16 + (lane&15)][dc*32 + (lane>>4)*8 + i]
__global__ __launch_bounds__(256) void build_At(const float* __restrict__ kern,
                                                _Float16* __restrict__ At) {
    int tid  = blockIdx.x * 256 + threadIdx.x;      // 786432 = 512*12288/8
    int lane = tid & 63;
    int rest = tid >> 6;                            // ft*384 + dc
    int dc   = rest % 384;
    int ft   = rest / 384;
    int f    = ft * 16 + (lane & 15);
    int d0   = dc * 32 + (lane >> 4) * 8;
    const float* src = kern + (size_t)f * LL + d0;
    half8 v;
#pragma unroll
    for (int i = 0; i < 8; ++i) v[i] = (_Float16)src[i];
    ((half8*)At)[tid] = v;
}

// ---------------- Prologue 2: B chunk-major layout --------------------------
// XB[jc][r] (16B chunks): r = s*8 + b, s in [0,16). elem_i = x_b[LL-1-(8jc+i)-s]
// (zero when index < 0 -> causal mask, incl. the whole jc >= 1536 pad tail).
__global__ __launch_bounds__(256) void build_XB(const int* __restrict__ ex,
                                                _Float16* __restrict__ XB) {
    int tid = blockIdx.x * 256 + threadIdx.x;       // 199168 = NJC*NR
    if (tid >= NJC * NR) return;
    int r  = tid & 127;
    int jc = tid >> 7;
    int s  = r >> 3, b = r & 7;
    int j0 = jc * 8;
    half8 v;
#pragma unroll
    for (int i = 0; i < 8; ++i) {
        int idx = LL - 1 - (j0 + i) - s;
        float x = 0.f;
        if (idx >= 0) x = (float)ex[b * LL + idx] * 0.5f - 1.0f;
        v[i] = (_Float16)x;
    }
    ((half8*)XB)[tid] = v;
}

// ---------------- Prologue 3: out = dense_b broadcast ----------------------
__global__ __launch_bounds__(256) void init_out(const float* __restrict__ db,
                                                float* __restrict__ out) {
    int tid = blockIdx.x * 256 + threadIdx.x;       // 393216
    out[tid] = db[tid & 3];
}

__device__ __forceinline__ void gl_lds16(const half8* g, half8* l) {
    __builtin_amdgcn_global_load_lds((const __attribute__((address_space(1))) void*)g,
                                     (__attribute__((address_space(3))) void*)l, 16, 0, 0);
}

// ---------------- Main: A via LDS (BK=128 macro-steps), B register-direct --
// Block 128f x 256cols, 4 waves, wave tile 128x64 (8x4 mfma 16x16x32 f16).
// One barrier per 4 K32 sub-steps: 32KB A tile double-buffered (64KB LDS).
// STAGGER: wave wid processes sub-steps in rotated order d=(s+wid)&3, so the
// 4 waves read different A quarters at any instant (spreads the post-barrier
// LDS burst 4x, interleaves MFMA bursts across waves on each SIMD).
// K rounded up to x4; tail MFMAs multiply by XB's zero pad (causal mask).
__global__ __launch_bounds__(256, 2) void conv_main(const _Float16* __restrict__ At,
                                                    const _Float16* __restrict__ XB,
                                                    const float* __restrict__ bias,
                                                    const float* __restrict__ dw,
                                                    float* __restrict__ out) {
    __shared__ half8 Abuf[2][4][8][64];   // 64 KB: [buf][sub][ft][lane]

    int bx    = blockIdx.x;
    int slot  = bx & 7;                // XCD pin: f_blk per XCD pair for L2 reuse
    int f_blk = slot >> 1;             // [0,4)
    int n_blk = 383 - ((bx >> 3) * 2 + (slot & 1));   // largest K first
    int n0 = n_blk << 5;
    int M  = (n_blk + 4) >> 2;         // ceil((n_blk+1)/4) macro (BK=128) steps

    int tid  = threadIdx.x;
    int lane = tid & 63;
    int wid  = tid >> 6;
    int quad = lane >> 4;
    int bb   = lane & 7;
    int nh   = (lane >> 3) & 1;

    // A staging: wave wid stages ft = wid and wid+4; 1KB contiguous per load.
    const half8* Ag  = (const half8*)At;
    const half8* ag0 = Ag + ((size_t)(f_blk * 8 + wid) * 384) * 64 + lane;
    const half8* ag1 = Ag + ((size_t)(f_blk * 8 + wid + 4) * 384) * 64 + lane;

    // B pointers (half8 units): idx = jc*128 + r; per-K32 advance = 4*128 = 512.
    const half8* Bg = (const half8*)XB;
    int jc0 = 1534 - 4 * n_blk + quad - 2 * nh;
    const half8* pB[4];
#pragma unroll
    for (int t = 0; t < 4; ++t) {
        int tt = wid * 4 + t;
        int r  = (15 - tt) * 8 + bb;
        pB[t] = Bg + (size_t)jc0 * 128 + r;
    }

    f32x4 acc[8][4];
#pragma unroll
    for (int r8 = 0; r8 < 8; ++r8)
#pragma unroll
        for (int t = 0; t < 4; ++t) acc[r8][t] = (f32x4){0.f, 0.f, 0.f, 0.f};

    // prologue: stage macro 0 -> buf0, load B for wave's first sub-step (d=wid)
#pragma unroll
    for (int sub = 0; sub < 4; ++sub) {
        gl_lds16(ag0 + (size_t)sub * 64, &Abuf[0][sub][wid][lane]);
        gl_lds16(ag1 + (size_t)sub * 64, &Abuf[0][sub][wid + 4][lane]);
    }
    half8 bcur[4], bnxt[4];
#pragma unroll
    for (int t = 0; t < 4; ++t) bcur[t] = pB[t][(size_t)wid * 512];
    __syncthreads();

    for (int mc = 0; mc < M; ++mc) {
        int buf = mc & 1;
        bool more = (mc + 1 < M);
        if (more) {
            size_t oa = (size_t)(mc + 1) * 256;           // 4 subs x 64 chunks
#pragma unroll
            for (int sub = 0; sub < 4; ++sub) {
                gl_lds16(ag0 + oa + (size_t)sub * 64, &Abuf[buf ^ 1][sub][wid][lane]);
                gl_lds16(ag1 + oa + (size_t)sub * 64, &Abuf[buf ^ 1][sub][wid + 4][lane]);
            }
        }
#pragma unroll
        for (int s = 0; s < 4; ++s) {
            int d = (s + wid) & 3;                        // this wave's sub-step
            // prefetch B for the wave's NEXT sub-step (next macro's first when s==3)
            int dn = ((s + 1 + wid) & 3) + ((s == 3) ? 4 : 0);
            if (s < 3 || more) {
                size_t obn = ((size_t)mc * 4 + dn) * 512;
#pragma unroll
                for (int t = 0; t < 4; ++t) bnxt[t] = pB[t][obn];
            }
            half8 a[8];
#pragma unroll
            for (int r8 = 0; r8 < 8; ++r8) a[r8] = Abuf[buf][d][r8][lane];
#pragma unroll
            for (int r8 = 0; r8 < 8; ++r8)
#pragma unroll
                for (int t = 0; t < 4; ++t)
                    acc[r8][t] = __builtin_amdgcn_mfma_f32_16x16x32_f16(a[r8], bcur[t], acc[r8][t], 0, 0, 0);
#pragma unroll
            for (int t = 0; t < 4; ++t) bcur[t] = bnxt[t];
        }
        __syncthreads();
    }

    // Epilogue: bias + relu + dense over this block's 128 f rows.
    // C/D layout: col = lane&15, row = quad*4 + reg.
    float p[4][4] = {{0.f}};
#pragma unroll
    for (int r8 = 0; r8 < 8; ++r8) {
#pragma unroll
        for (int reg = 0; reg < 4; ++reg) {
            int f = f_blk * 128 + r8 * 16 + quad * 4 + reg;
            float bs = bias[f];
            float4 w = *(const float4*)(dw + (size_t)f * 4);
#pragma unroll
            for (int t = 0; t < 4; ++t) {
                float y = fmaxf(acc[r8][t][reg] + bs, 0.f);
                p[t][0] += y * w.x; p[t][1] += y * w.y;
                p[t][2] += y * w.z; p[t][3] += y * w.w;
            }
        }
    }
#pragma unroll
    for (int t = 0; t < 4; ++t)
#pragma unroll
        for (int c = 0; c < 4; ++c) {
            float v = p[t][c];
            v += __shfl_xor(v, 16, 64);
            v += __shfl_xor(v, 32, 64);
            p[t][c] = v;
        }
    if (quad == 0) {
#pragma unroll
        for (int t = 0; t < 4; ++t) {
            int n = n0 + (wid * 4 + t) + 16 * nh;
            float* o = out + ((size_t)bb * LL + n) * 4;
#pragma unroll
            for (int c = 0; c < 4; ++c) atomicAdd(o + c, p[t][c]);
        }
    }
}

extern "C" void kernel_launch(void* const* d_in, const int* in_sizes, int n_in,
                              void* d_out, int out_size, void* d_ws, size_t ws_size,
                              hipStream_t stream) {
    const int*   ex   = (const int*)d_in[0];
    const float* kern = (const float*)d_in[1];
    const float* bias = (const float*)d_in[2];
    const float* dw   = (const float*)d_in[3];
    const float* db   = (const float*)d_in[4];
    float* out = (float*)d_out;

    _Float16* At = (_Float16*)d_ws;                                   // 12.58 MB
    _Float16* XB = (_Float16*)((char*)d_ws + (size_t)FF * LL * 2);    // +3.05 MB

    hipLaunchKernelGGL(build_At, dim3(3072), dim3(256), 0, stream, kern, At);
    hipLaunchKernelGGL(build_XB, dim3(778),  dim3(256), 0, stream, ex, XB);
    hipLaunchKernelGGL(init_out, dim3(1536), dim3(256), 0, stream, db, out);
    hipLaunchKernelGGL(conv_main, dim3(1536), dim3(256), 0, stream, At, XB, bias, dw, out);
}

// Round 5
// 523.189 us; speedup vs baseline: 1.0801x; 1.0065x over previous
//
#include <hip/hip_runtime.h>

#define FF 512
#define LL 12288
#define NJC 1556   // XB chunk count: max jc touched <= 1553 (incl. K-roundup + prefetch)
#define NR 128     // XB rows = 16 shifts x 8 batches

typedef _Float16 half8 __attribute__((ext_vector_type(8)));
typedef float    f32x4 __attribute__((ext_vector_type(4)));

// ---------------- Prologue 1: kernel fp32 -> f16, MFMA-A-fragment tiled ----
// At chunk (ft,dc,lane): elem_i = kernel[ft*16 + (lane&15)][dc*32 + (lane>>4)*8 + i]
__global__ __launch_bounds__(256) void build_At(const float* __restrict__ kern,
                                                _Float16* __restrict__ At) {
    int tid  = blockIdx.x * 256 + threadIdx.x;      // 786432 = 512*12288/8
    int lane = tid & 63;
    int rest = tid >> 6;                            // ft*384 + dc
    int dc   = rest % 384;
    int ft   = rest / 384;
    int f    = ft * 16 + (lane & 15);
    int d0   = dc * 32 + (lane >> 4) * 8;
    const float* src = kern + (size_t)f * LL + d0;
    half8 v;
#pragma unroll
    for (int i = 0; i < 8; ++i) v[i] = (_Float16)src[i];
    ((half8*)At)[tid] = v;
}

// ---------------- Prologue 2: B chunk-major layout --------------------------
// XB[jc][r] (16B chunks): r = s*8 + b, s in [0,16). elem_i = x_b[LL-1-(8jc+i)-s]
// (zero when index < 0 -> causal mask, incl. the whole jc >= 1536 pad tail).
__global__ __launch_bounds__(256) void build_XB(const int* __restrict__ ex,
                                                _Float16* __restrict__ XB) {
    int tid = blockIdx.x * 256 + threadIdx.x;       // 199168 = NJC*NR
    if (tid >= NJC * NR) return;
    int r  = tid & 127;
    int jc = tid >> 7;
    int s  = r >> 3, b = r & 7;
    int j0 = jc * 8;
    half8 v;
#pragma unroll
    for (int i = 0; i < 8; ++i) {
        int idx = LL - 1 - (j0 + i) - s;
        float x = 0.f;
        if (idx >= 0) x = (float)ex[b * LL + idx] * 0.5f - 1.0f;
        v[i] = (_Float16)x;
    }
    ((half8*)XB)[tid] = v;
}

// ---------------- Prologue 3: out = dense_b broadcast ----------------------
__global__ __launch_bounds__(256) void init_out(const float* __restrict__ db,
                                                float* __restrict__ out) {
    int tid = blockIdx.x * 256 + threadIdx.x;       // 393216
    out[tid] = db[tid & 3];
}

__device__ __forceinline__ void gl_lds16(const half8* g, half8* l) {
    __builtin_amdgcn_global_load_lds((const __attribute__((address_space(1))) void*)g,
                                     (__attribute__((address_space(3))) void*)l, 16, 0, 0);
}

// ---------------- Main: A via LDS ring (K64 units), B register-direct ------
// Block 128f x 256cols, 4 waves, wave tile 128x64 (8x4 mfma 16x16x32 f16).
// RING SCHEDULE (T4-minimal): LDS = ring of 4 units (16 KB each: 2 K32
// sub-steps), staged TWO units ahead via global_load_lds. Barrier per unit is
// s_waitcnt vmcnt(12) + s_barrier: "all vmem older than this unit's 12 ops
// (4 gl_lds + 8 B loads) retired" — guarantees the NEXT unit's staging (>=20
// ops old) landed, while this unit's B prefetch and 2-units-ahead staging stay
// in flight. No drain, no sched_barrier walls, no setprio.
// Staging is unconditional (constant vmem count per unit); tail overrun stays
// inside the workspace and multiplies XB's causal zero-pad.
__global__ __launch_bounds__(256, 2) void conv_main(const _Float16* __restrict__ At,
                                                    const _Float16* __restrict__ XB,
                                                    const float* __restrict__ bias,
                                                    const float* __restrict__ dw,
                                                    float* __restrict__ out) {
    __shared__ half8 Abuf[4][2][8][64];   // 64 KB ring: [unit&3][sub][ft][lane]

    int bx    = blockIdx.x;
    int slot  = bx & 7;                // XCD pin: f_blk per XCD pair for L2 reuse
    int f_blk = slot >> 1;             // [0,4)
    int n_blk = 383 - ((bx >> 3) * 2 + (slot & 1));   // largest K first
    int n0 = n_blk << 5;
    int U  = (n_blk + 2) >> 1;         // ceil((n_blk+1)/2) units of K=64

    int tid  = threadIdx.x;
    int lane = tid & 63;
    int wid  = tid >> 6;
    int quad = lane >> 4;
    int bb   = lane & 7;
    int nh   = (lane >> 3) & 1;

    // A staging: wave wid stages ft = wid and wid+4; unit k data at +k*128.
    const half8* Ag  = (const half8*)At;
    const half8* ag0 = Ag + ((size_t)(f_blk * 8 + wid) * 384) * 64 + lane;
    const half8* ag1 = Ag + ((size_t)(f_blk * 8 + wid + 4) * 384) * 64 + lane;

    // B pointers (half8 units): idx = jc*128 + r; per-K32 advance = 512.
    const half8* Bg = (const half8*)XB;
    int jc0 = 1534 - 4 * n_blk + quad - 2 * nh;
    const half8* pB[4];
#pragma unroll
    for (int t = 0; t < 4; ++t) {
        int tt = wid * 4 + t;
        int r  = (15 - tt) * 8 + bb;
        pB[t] = Bg + (size_t)jc0 * 128 + r;
    }

    f32x4 acc[8][4];
#pragma unroll
    for (int r8 = 0; r8 < 8; ++r8)
#pragma unroll
        for (int t = 0; t < 4; ++t) acc[r8][t] = (f32x4){0.f, 0.f, 0.f, 0.f};

    // prologue: stage units 0 and 1; load B(sub 0); advance pB to sub 1
#pragma unroll
    for (int uu = 0; uu < 2; ++uu)
#pragma unroll
        for (int sub = 0; sub < 2; ++sub) {
            gl_lds16(ag0 + (size_t)(uu * 2 + sub) * 64, &Abuf[uu][sub][wid][lane]);
            gl_lds16(ag1 + (size_t)(uu * 2 + sub) * 64, &Abuf[uu][sub][wid + 4][lane]);
        }
    half8 bcur[4], bnxt[4];
#pragma unroll
    for (int t = 0; t < 4; ++t) { bcur[t] = pB[t][0]; pB[t] += 512; }
    asm volatile("s_waitcnt vmcnt(0)" ::: "memory");
    __builtin_amdgcn_s_barrier();

    for (int u = 0; u < U; ++u) {
        // stage unit u+2 into ring slot (u+2)&3 (4 gl_lds; unconditional)
        int rs = (u + 2) & 3;
        size_t os = (size_t)(u + 2) * 128;
        gl_lds16(ag0 + os,      &Abuf[rs][0][wid][lane]);
        gl_lds16(ag0 + os + 64, &Abuf[rs][1][wid][lane]);
        gl_lds16(ag1 + os,      &Abuf[rs][0][wid + 4][lane]);
        gl_lds16(ag1 + os + 64, &Abuf[rs][1][wid + 4][lane]);

        int rc = u & 3;
#pragma unroll
        for (int s = 0; s < 2; ++s) {
#pragma unroll
            for (int t = 0; t < 4; ++t) { bnxt[t] = pB[t][0]; pB[t] += 512; }
            half8 a[8];
#pragma unroll
            for (int r8 = 0; r8 < 8; ++r8) a[r8] = Abuf[rc][s][r8][lane];
#pragma unroll
            for (int r8 = 0; r8 < 8; ++r8)
#pragma unroll
                for (int t = 0; t < 4; ++t)
                    acc[r8][t] = __builtin_amdgcn_mfma_f32_16x16x32_f16(a[r8], bcur[t], acc[r8][t], 0, 0, 0);
#pragma unroll
            for (int t = 0; t < 4; ++t) bcur[t] = bnxt[t];
        }

        // counted barrier: unit u issued 12 vmem ops (4 gl_lds + 8 B); waiting
        // to <=12 outstanding retires everything older (incl. unit u+1 staging).
        asm volatile("s_waitcnt vmcnt(12)" ::: "memory");
        __builtin_amdgcn_s_barrier();
    }

    // Epilogue: bias + relu + dense over this block's 128 f rows.
    // C/D layout: col = lane&15, row = quad*4 + reg.
    float p[4][4] = {{0.f}};
#pragma unroll
    for (int r8 = 0; r8 < 8; ++r8) {
#pragma unroll
        for (int reg = 0; reg < 4; ++reg) {
            int f = f_blk * 128 + r8 * 16 + quad * 4 + reg;
            float bs = bias[f];
            float4 w = *(const float4*)(dw + (size_t)f * 4);
#pragma unroll
            for (int t = 0; t < 4; ++t) {
                float y = fmaxf(acc[r8][t][reg] + bs, 0.f);
                p[t][0] += y * w.x; p[t][1] += y * w.y;
                p[t][2] += y * w.z; p[t][3] += y * w.w;
            }
        }
    }
#pragma unroll
    for (int t = 0; t < 4; ++t)
#pragma unroll
        for (int c = 0; c < 4; ++c) {
            float v = p[t][c];
            v += __shfl_xor(v, 16, 64);
            v += __shfl_xor(v, 32, 64);
            p[t][c] = v;
        }
    if (quad == 0) {
#pragma unroll
        for (int t = 0; t < 4; ++t) {
            int n = n0 + (wid * 4 + t) + 16 * nh;
            float* o = out + ((size_t)bb * LL + n) * 4;
#pragma unroll
            for (int c = 0; c < 4; ++c) atomicAdd(o + c, p[t][c]);
        }
    }
}

extern "C" void kernel_launch(void* const* d_in, const int* in_sizes, int n_in,
                              void* d_out, int out_size, void* d_ws, size_t ws_size,
                              hipStream_t stream) {
    const int*   ex   = (const int*)d_in[0];
    const float* kern = (const float*)d_in[1];
    const float* bias = (const float*)d_in[2];
    const float* dw   = (const float*)d_in[3];
    const float* db   = (const float*)d_in[4];
    float* out = (float*)d_out;

    _Float16* At = (_Float16*)d_ws;                                   // 12.58 MB
    _Float16* XB = (_Float16*)((char*)d_ws + (size_t)FF * LL * 2);    // +3.05 MB

    hipLaunchKernelGGL(build_At, dim3(3072), dim3(256), 0, stream, kern, At);
    hipLaunchKernelGGL(build_XB, dim3(778),  dim3(256), 0, stream, ex, XB);
    hipLaunchKernelGGL(init_out, dim3(1536), dim3(256), 0, stream, db, out);
    hipLaunchKernelGGL(conv_main, dim3(1536), dim3(256), 0, stream, At, XB, bias, dw, out);
}

// Round 6
// 511.512 us; speedup vs baseline: 1.1047x; 1.0228x over previous
//
#include <hip/hip_runtime.h>

#define FF 512
#define LL 12288
#define NJC 1556   // XB chunk count: max jc touched = 1553 (incl. K-roundup + prefetch)
#define NR 128     // XB rows = 16 shifts x 8 batches

typedef _Float16 half8 __attribute__((ext_vector_type(8)));
typedef float    f32x4 __attribute__((ext_vector_type(4)));

// ---------------- Prologue 1: kernel fp32 -> f16, MFMA-A-fragment tiled ----
// At chunk (ft,dc,lane): elem_i = kernel[ft*16 + (lane&15)][dc*32 + (lane>>4)*8 + i]
__global__ __launch_bounds__(256) void build_At(const float* __restrict__ kern,
                                                _Float16* __restrict__ At) {
    int tid  = blockIdx.x * 256 + threadIdx.x;      // 786432 = 512*12288/8
    int lane = tid & 63;
    int rest = tid >> 6;                            // ft*384 + dc
    int dc   = rest % 384;
    int ft   = rest / 384;
    int f    = ft * 16 + (lane & 15);
    int d0   = dc * 32 + (lane >> 4) * 8;
    const float* src = kern + (size_t)f * LL + d0;
    half8 v;
#pragma unroll
    for (int i = 0; i < 8; ++i) v[i] = (_Float16)src[i];
    ((half8*)At)[tid] = v;
}

// ---------------- Prologue 2: B chunk-major layout --------------------------
// XB[jc][r] (16B chunks): r = s*8 + b, s in [0,16). elem_i = x_b[LL-1-(8jc+i)-s]
// (zero when index < 0 -> causal mask, incl. the whole jc >= 1536 pad tail).
__global__ __launch_bounds__(256) void build_XB(const int* __restrict__ ex,
                                                _Float16* __restrict__ XB) {
    int tid = blockIdx.x * 256 + threadIdx.x;       // 199168 = NJC*NR
    if (tid >= NJC * NR) return;
    int r  = tid & 127;
    int jc = tid >> 7;
    int s  = r >> 3, b = r & 7;
    int j0 = jc * 8;
    half8 v;
#pragma unroll
    for (int i = 0; i < 8; ++i) {
        int idx = LL - 1 - (j0 + i) - s;
        float x = 0.f;
        if (idx >= 0) x = (float)ex[b * LL + idx] * 0.5f - 1.0f;
        v[i] = (_Float16)x;
    }
    ((half8*)XB)[tid] = v;
}

// ---------------- Prologue 3: out = dense_b broadcast ----------------------
__global__ __launch_bounds__(256) void init_out(const float* __restrict__ db,
                                                float* __restrict__ out) {
    int tid = blockIdx.x * 256 + threadIdx.x;       // 393216
    out[tid] = db[tid & 3];
}

__device__ __forceinline__ void gl_lds16(const half8* g, half8* l) {
    __builtin_amdgcn_global_load_lds((const __attribute__((address_space(1))) void*)g,
                                     (__attribute__((address_space(3))) void*)l, 16, 0, 0);
}

// ---------------- Main: A via LDS (BK=128 macro-steps), B register-direct --
// Block 128f x 256cols, 4 waves, wave tile 128x64 (8x4 mfma 16x16x32 f16).
// One __syncthreads per 4 K32 sub-steps; 32KB A tile double-buffered (64KB).
// PHASE-INTERLOCK (surgical T5): each sub-step's 32-MFMA cluster is fenced by
// s_barrier pairs and wrapped in setprio(1). The block's 4 waves enter/leave
// MFMA clusters together, creating a clean {MFMA-phase vs load-phase} split
// between the TWO co-resident blocks on each SIMD; setprio biases issue to
// the MFMA-phase wave. No sched_barrier walls, no manual waitcnt (compiler's
// fine-grained lgkmcnt stands). K rounded up to x4; tail MFMAs multiply by
// XB's zero pad (causal mask).
__global__ __launch_bounds__(256, 2) void conv_main(const _Float16* __restrict__ At,
                                                    const _Float16* __restrict__ XB,
                                                    const float* __restrict__ bias,
                                                    const float* __restrict__ dw,
                                                    float* __restrict__ out) {
    __shared__ half8 Abuf[2][4][8][64];   // 64 KB: [buf][sub][ft][lane]

    int bx    = blockIdx.x;
    int slot  = bx & 7;                // XCD pin: f_blk per XCD pair for L2 reuse
    int f_blk = slot >> 1;             // [0,4)
    int n_blk = 383 - ((bx >> 3) * 2 + (slot & 1));   // largest K first
    int n0 = n_blk << 5;
    int M  = (n_blk + 4) >> 2;         // ceil((n_blk+1)/4) macro (BK=128) steps

    int tid  = threadIdx.x;
    int lane = tid & 63;
    int wid  = tid >> 6;
    int quad = lane >> 4;
    int bb   = lane & 7;
    int nh   = (lane >> 3) & 1;

    // A staging: wave wid stages ft = wid and wid+4; 1KB contiguous per load.
    const half8* Ag  = (const half8*)At;
    const half8* ag0 = Ag + ((size_t)(f_blk * 8 + wid) * 384) * 64 + lane;
    const half8* ag1 = Ag + ((size_t)(f_blk * 8 + wid + 4) * 384) * 64 + lane;

    // B pointers (half8 units): idx = jc*128 + r; per-K32 advance = 4*128 = 512.
    const half8* Bg = (const half8*)XB;
    int jc0 = 1534 - 4 * n_blk + quad - 2 * nh;
    const half8* pB[4];
#pragma unroll
    for (int t = 0; t < 4; ++t) {
        int tt = wid * 4 + t;
        int r  = (15 - tt) * 8 + bb;
        pB[t] = Bg + (size_t)jc0 * 128 + r;
    }

    f32x4 acc[8][4];
#pragma unroll
    for (int r8 = 0; r8 < 8; ++r8)
#pragma unroll
        for (int t = 0; t < 4; ++t) acc[r8][t] = (f32x4){0.f, 0.f, 0.f, 0.f};

    // prologue: stage macro 0 -> buf0, load B(0)
#pragma unroll
    for (int sub = 0; sub < 4; ++sub) {
        gl_lds16(ag0 + (size_t)sub * 64, &Abuf[0][sub][wid][lane]);
        gl_lds16(ag1 + (size_t)sub * 64, &Abuf[0][sub][wid + 4][lane]);
    }
    half8 bcur[4], bnxt[4];
#pragma unroll
    for (int t = 0; t < 4; ++t) bcur[t] = pB[t][0];
    __syncthreads();

    for (int mc = 0; mc < M; ++mc) {
        int buf = mc & 1;
        if (mc + 1 < M) {
            size_t oa = (size_t)(mc + 1) * 256;           // 4 subs x 64 chunks
#pragma unroll
            for (int sub = 0; sub < 4; ++sub) {
                gl_lds16(ag0 + oa + (size_t)sub * 64, &Abuf[buf ^ 1][sub][wid][lane]);
                gl_lds16(ag1 + oa + (size_t)sub * 64, &Abuf[buf ^ 1][sub][wid + 4][lane]);
            }
        }
#pragma unroll
        for (int sub = 0; sub < 4; ++sub) {
            int dc = mc * 4 + sub;
            size_t ob = (size_t)(dc + 1) * 512;
#pragma unroll
            for (int t = 0; t < 4; ++t) bnxt[t] = pB[t][ob];
            half8 a[8];
#pragma unroll
            for (int r8 = 0; r8 < 8; ++r8) a[r8] = Abuf[buf][sub][r8][lane];
            __builtin_amdgcn_s_barrier();          // cluster entry: waves aligned
            __builtin_amdgcn_s_setprio(1);
#pragma unroll
            for (int r8 = 0; r8 < 8; ++r8)
#pragma unroll
                for (int t = 0; t < 4; ++t)
                    acc[r8][t] = __builtin_amdgcn_mfma_f32_16x16x32_f16(a[r8], bcur[t], acc[r8][t], 0, 0, 0);
            __builtin_amdgcn_s_setprio(0);
            __builtin_amdgcn_s_barrier();          // cluster exit
#pragma unroll
            for (int t = 0; t < 4; ++t) bcur[t] = bnxt[t];
        }
        __syncthreads();
    }

    // Epilogue: bias + relu + dense over this block's 128 f rows.
    // C/D layout: col = lane&15, row = quad*4 + reg.
    float p[4][4] = {{0.f}};
#pragma unroll
    for (int r8 = 0; r8 < 8; ++r8) {
#pragma unroll
        for (int reg = 0; reg < 4; ++reg) {
            int f = f_blk * 128 + r8 * 16 + quad * 4 + reg;
            float bs = bias[f];
            float4 w = *(const float4*)(dw + (size_t)f * 4);
#pragma unroll
            for (int t = 0; t < 4; ++t) {
                float y = fmaxf(acc[r8][t][reg] + bs, 0.f);
                p[t][0] += y * w.x; p[t][1] += y * w.y;
                p[t][2] += y * w.z; p[t][3] += y * w.w;
            }
        }
    }
#pragma unroll
    for (int t = 0; t < 4; ++t)
#pragma unroll
        for (int c = 0; c < 4; ++c) {
            float v = p[t][c];
            v += __shfl_xor(v, 16, 64);
            v += __shfl_xor(v, 32, 64);
            p[t][c] = v;
        }
    if (quad == 0) {
#pragma unroll
        for (int t = 0; t < 4; ++t) {
            int n = n0 + (wid * 4 + t) + 16 * nh;
            float* o = out + ((size_t)bb * LL + n) * 4;
#pragma unroll
            for (int c = 0; c < 4; ++c) atomicAdd(o + c, p[t][c]);
        }
    }
}

extern "C" void kernel_launch(void* const* d_in, const int* in_sizes, int n_in,
                              void* d_out, int out_size, void* d_ws, size_t ws_size,
                              hipStream_t stream) {
    const int*   ex   = (const int*)d_in[0];
    const float* kern = (const float*)d_in[1];
    const float* bias = (const float*)d_in[2];
    const float* dw   = (const float*)d_in[3];
    const float* db   = (const float*)d_in[4];
    float* out = (float*)d_out;

    _Float16* At = (_Float16*)d_ws;                                   // 12.58 MB
    _Float16* XB = (_Float16*)((char*)d_ws + (size_t)FF * LL * 2);    // +3.05 MB

    hipLaunchKernelGGL(build_At, dim3(3072), dim3(256), 0, stream, kern, At);
    hipLaunchKernelGGL(build_XB, dim3(778),  dim3(256), 0, stream, ex, XB);
    hipLaunchKernelGGL(init_out, dim3(1536), dim3(256), 0, stream, db, out);
    hipLaunchKernelGGL(conv_main, dim3(1536), dim3(256), 0, stream, At, XB, bias, dw, out);
}

// Round 7
// 502.676 us; speedup vs baseline: 1.1242x; 1.0176x over previous
//
#include <hip/hip_runtime.h>

#define FF 512
#define LL 12288
#define NJC 1556   // XB chunk count: max jc touched = 1553 (incl. K-roundup + prefetch)
#define NR 128     // XB rows = 16 shifts x 8 batches

typedef _Float16 half8 __attribute__((ext_vector_type(8)));
typedef float    f32x4 __attribute__((ext_vector_type(4)));

// ---------------- Fused prologue: 3 ranges of blockIdx, disjoint outputs ----
// [0,3072)        build_At : kernel fp32 -> f16, MFMA-A-fragment tiled
//                  At chunk (ft,dc,lane): elem_i = kernel[ft*16+(lane&15)][dc*32+(lane>>4)*8+i]
// [3072,3850)     build_XB : B chunk-major; XB[jc][s*8+b] elem_i = x_b[LL-1-(8jc+i)-s]
//                  (zero when idx<0 -> causal mask, incl. jc>=1536 pad tail)
// [3850,5386)     init_out : out = dense_b broadcast
__global__ __launch_bounds__(256) void prologue(const float* __restrict__ kern,
                                                _Float16* __restrict__ At,
                                                const int* __restrict__ ex,
                                                _Float16* __restrict__ XB,
                                                const float* __restrict__ db,
                                                float* __restrict__ out) {
    int bxx = blockIdx.x;
    if (bxx < 3072) {
        int tid  = bxx * 256 + threadIdx.x;             // 786432 = 512*12288/8
        int lane = tid & 63;
        int rest = tid >> 6;                            // ft*384 + dc
        int dc   = rest % 384;
        int ft   = rest / 384;
        int f    = ft * 16 + (lane & 15);
        int d0   = dc * 32 + (lane >> 4) * 8;
        const float* src = kern + (size_t)f * LL + d0;
        half8 v;
#pragma unroll
        for (int i = 0; i < 8; ++i) v[i] = (_Float16)src[i];
        ((half8*)At)[tid] = v;
    } else if (bxx < 3850) {
        int tid = (bxx - 3072) * 256 + threadIdx.x;     // 199168 = NJC*NR
        if (tid >= NJC * NR) return;
        int r  = tid & 127;
        int jc = tid >> 7;
        int s  = r >> 3, b = r & 7;
        int j0 = jc * 8;
        half8 v;
#pragma unroll
        for (int i = 0; i < 8; ++i) {
            int idx = LL - 1 - (j0 + i) - s;
            float x = 0.f;
            if (idx >= 0) x = (float)ex[b * LL + idx] * 0.5f - 1.0f;
            v[i] = (_Float16)x;
        }
        ((half8*)XB)[tid] = v;
    } else {
        int tid = (bxx - 3850) * 256 + threadIdx.x;     // 393216
        out[tid] = db[tid & 3];
    }
}

__device__ __forceinline__ void gl_lds16(const half8* g, half8* l) {
    __builtin_amdgcn_global_load_lds((const __attribute__((address_space(1))) void*)g,
                                     (__attribute__((address_space(3))) void*)l, 16, 0, 0);
}

// ---------------- Main: A via LDS (BK=128 macro-steps), B register-direct --
// Block 128f x 256cols, 4 waves, wave tile 128x64 (8x4 mfma 16x16x32 f16).
// One __syncthreads per 4 K32 sub-steps; 32KB A tile double-buffered (64KB).
// PHASE-INTERLOCK (T5, entry-only): each sub-step's 32-MFMA cluster starts at
// an s_barrier and runs at setprio(1). Entry barrier keeps the block's 4 waves
// phase-locked (creating a {MFMA-phase vs load-phase} split between the two
// co-resident blocks per SIMD); no exit barrier — fast waves overlap their
// next-sub-step loads with siblings' MFMA tails. No sched_barrier walls, no
// manual waitcnt. K rounded up to x4; tail MFMAs hit XB's causal zero pad.
__global__ __launch_bounds__(256, 2) void conv_main(const _Float16* __restrict__ At,
                                                    const _Float16* __restrict__ XB,
                                                    const float* __restrict__ bias,
                                                    const float* __restrict__ dw,
                                                    float* __restrict__ out) {
    __shared__ half8 Abuf[2][4][8][64];   // 64 KB: [buf][sub][ft][lane]

    int bx    = blockIdx.x;
    int slot  = bx & 7;                // XCD pin: f_blk per XCD pair for L2 reuse
    int f_blk = slot >> 1;             // [0,4)
    int n_blk = 383 - ((bx >> 3) * 2 + (slot & 1));   // largest K first
    int n0 = n_blk << 5;
    int M  = (n_blk + 4) >> 2;         // ceil((n_blk+1)/4) macro (BK=128) steps

    int tid  = threadIdx.x;
    int lane = tid & 63;
    int wid  = tid >> 6;
    int quad = lane >> 4;
    int bb   = lane & 7;
    int nh   = (lane >> 3) & 1;

    // A staging: wave wid stages ft = wid and wid+4; 1KB contiguous per load.
    const half8* Ag  = (const half8*)At;
    const half8* ag0 = Ag + ((size_t)(f_blk * 8 + wid) * 384) * 64 + lane;
    const half8* ag1 = Ag + ((size_t)(f_blk * 8 + wid + 4) * 384) * 64 + lane;

    // B pointers (half8 units): idx = jc*128 + r; per-K32 advance = 4*128 = 512.
    const half8* Bg = (const half8*)XB;
    int jc0 = 1534 - 4 * n_blk + quad - 2 * nh;
    const half8* pB[4];
#pragma unroll
    for (int t = 0; t < 4; ++t) {
        int tt = wid * 4 + t;
        int r  = (15 - tt) * 8 + bb;
        pB[t] = Bg + (size_t)jc0 * 128 + r;
    }

    f32x4 acc[8][4];
#pragma unroll
    for (int r8 = 0; r8 < 8; ++r8)
#pragma unroll
        for (int t = 0; t < 4; ++t) acc[r8][t] = (f32x4){0.f, 0.f, 0.f, 0.f};

    // prologue: stage macro 0 -> buf0, load B(0)
#pragma unroll
    for (int sub = 0; sub < 4; ++sub) {
        gl_lds16(ag0 + (size_t)sub * 64, &Abuf[0][sub][wid][lane]);
        gl_lds16(ag1 + (size_t)sub * 64, &Abuf[0][sub][wid + 4][lane]);
    }
    half8 bcur[4], bnxt[4];
#pragma unroll
    for (int t = 0; t < 4; ++t) bcur[t] = pB[t][0];
    __syncthreads();

    for (int mc = 0; mc < M; ++mc) {
        int buf = mc & 1;
        if (mc + 1 < M) {
            size_t oa = (size_t)(mc + 1) * 256;           // 4 subs x 64 chunks
#pragma unroll
            for (int sub = 0; sub < 4; ++sub) {
                gl_lds16(ag0 + oa + (size_t)sub * 64, &Abuf[buf ^ 1][sub][wid][lane]);
                gl_lds16(ag1 + oa + (size_t)sub * 64, &Abuf[buf ^ 1][sub][wid + 4][lane]);
            }
        }
#pragma unroll
        for (int sub = 0; sub < 4; ++sub) {
            int dc = mc * 4 + sub;
            size_t ob = (size_t)(dc + 1) * 512;
#pragma unroll
            for (int t = 0; t < 4; ++t) bnxt[t] = pB[t][ob];
            half8 a[8];
#pragma unroll
            for (int r8 = 0; r8 < 8; ++r8) a[r8] = Abuf[buf][sub][r8][lane];
            __builtin_amdgcn_s_barrier();          // cluster entry: waves aligned
            __builtin_amdgcn_s_setprio(1);
#pragma unroll
            for (int r8 = 0; r8 < 8; ++r8)
#pragma unroll
                for (int t = 0; t < 4; ++t)
                    acc[r8][t] = __builtin_amdgcn_mfma_f32_16x16x32_f16(a[r8], bcur[t], acc[r8][t], 0, 0, 0);
            __builtin_amdgcn_s_setprio(0);
#pragma unroll
            for (int t = 0; t < 4; ++t) bcur[t] = bnxt[t];
        }
        __syncthreads();
    }

    // Epilogue: bias + relu + dense over this block's 128 f rows.
    // C/D layout: col = lane&15, row = quad*4 + reg.
    float p[4][4] = {{0.f}};
#pragma unroll
    for (int r8 = 0; r8 < 8; ++r8) {
#pragma unroll
        for (int reg = 0; reg < 4; ++reg) {
            int f = f_blk * 128 + r8 * 16 + quad * 4 + reg;
            float bs = bias[f];
            float4 w = *(const float4*)(dw + (size_t)f * 4);
#pragma unroll
            for (int t = 0; t < 4; ++t) {
                float y = fmaxf(acc[r8][t][reg] + bs, 0.f);
                p[t][0] += y * w.x; p[t][1] += y * w.y;
                p[t][2] += y * w.z; p[t][3] += y * w.w;
            }
        }
    }
#pragma unroll
    for (int t = 0; t < 4; ++t)
#pragma unroll
        for (int c = 0; c < 4; ++c) {
            float v = p[t][c];
            v += __shfl_xor(v, 16, 64);
            v += __shfl_xor(v, 32, 64);
            p[t][c] = v;
        }
    if (quad == 0) {
#pragma unroll
        for (int t = 0; t < 4; ++t) {
            int n = n0 + (wid * 4 + t) + 16 * nh;
            float* o = out + ((size_t)bb * LL + n) * 4;
#pragma unroll
            for (int c = 0; c < 4; ++c) atomicAdd(o + c, p[t][c]);
        }
    }
}

extern "C" void kernel_launch(void* const* d_in, const int* in_sizes, int n_in,
                              void* d_out, int out_size, void* d_ws, size_t ws_size,
                              hipStream_t stream) {
    const int*   ex   = (const int*)d_in[0];
    const float* kern = (const float*)d_in[1];
    const float* bias = (const float*)d_in[2];
    const float* dw   = (const float*)d_in[3];
    const float* db   = (const float*)d_in[4];
    float* out = (float*)d_out;

    _Float16* At = (_Float16*)d_ws;                                   // 12.58 MB
    _Float16* XB = (_Float16*)((char*)d_ws + (size_t)FF * LL * 2);    // +3.05 MB

    hipLaunchKernelGGL(prologue, dim3(5386), dim3(256), 0, stream,
                       kern, At, ex, XB, db, out);
    hipLaunchKernelGGL(conv_main, dim3(1536), dim3(256), 0, stream, At, XB, bias, dw, out);
}